// Round 2
// baseline (154.255 us; speedup 1.0000x reference)
//
#include <hip/hip_runtime.h>
#include <hip/hip_bf16.h>
#include <math.h>

#define DD 48
#define NN 512
#define TWO_D 96
#define ROWS 2048   // B*N = 4*512

typedef __attribute__((ext_vector_type(8))) short bf16x8;
typedef __attribute__((ext_vector_type(4))) float f32x4;

// Kernel 1: A[r][t] = x_r @ W1[0:48, t] + b1[t];  Bb[r][t] = x_r @ W1[48:96, t]
__global__ void precompute_kernel(const float* __restrict__ x,
                                  const float* __restrict__ W1,
                                  const float* __restrict__ b1,
                                  float* __restrict__ Aout,
                                  float* __restrict__ Bout) {
    const int row = blockIdx.x;
    const int t = threadIdx.x;   // 0..95
    __shared__ float xs[DD];
    if (t < DD) xs[t] = x[row * DD + t];
    __syncthreads();
    float a0 = 0.f, a1 = 0.f;
#pragma unroll
    for (int k = 0; k < DD; ++k) {
        const float xv = xs[k];
        a0 = fmaf(xv, W1[k * TWO_D + t], a0);
        a1 = fmaf(xv, W1[(DD + k) * TWO_D + t], a1);
    }
    Aout[row * TWO_D + t] = a0 + b1[t];
    Bout[row * TWO_D + t] = a1;
}

// Kernel 2: one block per (b,i) row. 4 waves; wave w handles j-chunks w, w+4, ...
// Each chunk: H[16][96] = gelu(A_i + Bb_j) in private LDS (bf16), then
// P[16][48] = H @ W2 via 9 MFMA (3 f-tiles x 3 K-steps), then online softmax.
__global__ __launch_bounds__(256) void pair_softmax_kernel(
        const float* __restrict__ Arow,
        const float* __restrict__ Brow,
        const float* __restrict__ W2,
        const float* __restrict__ b2,
        float* __restrict__ out) {
    const int row = blockIdx.x;
    const int i = row & (NN - 1);
    const int tid = threadIdx.x;
    const int wave = tid >> 6;
    const int lane = tid & 63;
    const int n = lane & 15;   // MFMA: A-row index / C col index
    const int q = lane >> 4;   // quad

    // j rows live in the SAME batch: global j-row = (row - i) + j
    const float* __restrict__ Bbase = Brow + (size_t)(row - i) * TWO_D;

    __shared__ __align__(16) __hip_bfloat16 W2Ts[DD * TWO_D];   // [f][k], 9216 B
    __shared__ __align__(16) __hip_bfloat16 Hs[4][16 * TWO_D];  // per-wave H, 3072 B each
    __shared__ float As[TWO_D];
    __shared__ float mred[4], lred[4], ored[4][DD];

    // Stage W2^T (bf16) and A_i (fp32) into LDS
    for (int idx = tid; idx < TWO_D * DD; idx += 256) {
        const int k = idx / DD;
        const int f = idx - k * DD;
        W2Ts[f * TWO_D + k] = __float2bfloat16(W2[idx]);
    }
    if (tid < TWO_D) As[tid] = Arow[row * TWO_D + tid];
    __syncthreads();

    // Preload B fragments: B[k][f], lane n = f (col), k = ks*32 + q*8 + 0..7
    bf16x8 bfrag[3][3];
#pragma unroll
    for (int t = 0; t < 3; ++t)
#pragma unroll
        for (int ks = 0; ks < 3; ++ks)
            bfrag[t][ks] = *(const bf16x8*)&W2Ts[(t * 16 + n) * TWO_D + ks * 32 + q * 8];
    float b2v[3];
#pragma unroll
    for (int t = 0; t < 3; ++t) b2v[t] = b2[t * 16 + n];

    float m_run = -INFINITY, l_run = 0.f;
    float o_run[3] = {0.f, 0.f, 0.f};

    const int nchunks = (i + 16) >> 4;   // ceil((i+1)/16); last j index <= 511 always
    __hip_bfloat16* hbuf = &Hs[wave][0];

    for (int c = wave; c < nchunks; c += 4) {
        const int j0 = c << 4;
        // ---- Phase A: H = gelu(A_i + Bb_j), 16x96 elems as 768 float2 / 64 lanes
#pragma unroll
        for (int p = 0; p < 12; ++p) {
            const int e2 = lane + (p << 6);        // 0..767
            const int jj = e2 / 48;
            const int kk = (e2 - jj * 48) * 2;
            const float2 bv = *(const float2*)&Bbase[(j0 + jj) * TWO_D + kk];
            const float2 av = *(const float2*)&As[kk];
            const float p0 = av.x + bv.x;
            const float p1 = av.y + bv.y;
            const float h0 = 0.5f * p0 * (1.f + erff(p0 * 0.70710678118654752f));
            const float h1 = 0.5f * p1 * (1.f + erff(p1 * 0.70710678118654752f));
            __hip_bfloat162 hv;
            hv.x = __float2bfloat16(h0);
            hv.y = __float2bfloat16(h1);
            *(__hip_bfloat162*)&hbuf[jj * TWO_D + kk] = hv;
        }
        // wave-local LDS drain (writes above are read below by the SAME wave only)
        asm volatile("s_waitcnt lgkmcnt(0)" ::: "memory");

        // ---- Phase B: P = H @ W2   (A-frag: row m=n, k = ks*32 + q*8 + 0..7)
        f32x4 acc[3] = {{0.f,0.f,0.f,0.f},{0.f,0.f,0.f,0.f},{0.f,0.f,0.f,0.f}};
#pragma unroll
        for (int ks = 0; ks < 3; ++ks) {
            const bf16x8 af = *(const bf16x8*)&hbuf[n * TWO_D + ks * 32 + q * 8];
            acc[0] = __builtin_amdgcn_mfma_f32_16x16x32_bf16(af, bfrag[0][ks], acc[0], 0, 0, 0);
            acc[1] = __builtin_amdgcn_mfma_f32_16x16x32_bf16(af, bfrag[1][ks], acc[1], 0, 0, 0);
            acc[2] = __builtin_amdgcn_mfma_f32_16x16x32_bf16(af, bfrag[2][ks], acc[2], 0, 0, 0);
        }

        // ---- Epilogue: C/D layout row j_local = 4q+r, col f = t*16+n
        float pv[3][4];
        float ss[4];
#pragma unroll
        for (int r = 0; r < 4; ++r) {
            float s = 0.f;
#pragma unroll
            for (int t = 0; t < 3; ++t) {
                const float p = acc[t][r] + b2v[t];
                pv[t][r] = p;
                s = fmaf(p, p, s);
            }
            ss[r] = s;
        }
        // sum of squares over all 48 f: reduce across the 16 lanes of the quad
#pragma unroll
        for (int d = 1; d <= 8; d <<= 1) {
#pragma unroll
            for (int r = 0; r < 4; ++r) ss[r] += __shfl_xor(ss[r], d);
        }
        float w[4];
#pragma unroll
        for (int r = 0; r < 4; ++r) {
            const int j = j0 + 4 * q + r;
            w[r] = (j <= i) ? sqrtf(ss[r]) : -1e30f;
        }
        float wm = fmaxf(fmaxf(w[0], w[1]), fmaxf(w[2], w[3]));
        wm = fmaxf(wm, __shfl_xor(wm, 16));
        wm = fmaxf(wm, __shfl_xor(wm, 32));
        const float mnew = fmaxf(m_run, wm);          // >= 0 always (norms >= 0)
        const float alpha = expf(m_run - mnew);       // first chunk: exp(-inf)=0, l/o are 0
        float ew[4];
#pragma unroll
        for (int r = 0; r < 4; ++r) ew[r] = expf(w[r] - mnew);  // masked -> 0 exactly
        float es = ew[0] + ew[1] + ew[2] + ew[3];
        es += __shfl_xor(es, 16);
        es += __shfl_xor(es, 32);
        l_run = l_run * alpha + es;
#pragma unroll
        for (int t = 0; t < 3; ++t) {
            float op = ew[0]*pv[t][0] + ew[1]*pv[t][1] + ew[2]*pv[t][2] + ew[3]*pv[t][3];
            op += __shfl_xor(op, 16);
            op += __shfl_xor(op, 32);
            o_run[t] = o_run[t] * alpha + op;
        }
        m_run = mnew;
    }

    // ---- Merge the 4 per-wave online-softmax states
    if (lane == 0) { mred[wave] = m_run; lred[wave] = l_run; }
    if (q == 0) {
#pragma unroll
        for (int t = 0; t < 3; ++t) ored[wave][t * 16 + n] = o_run[t];
    }
    __syncthreads();
    if (tid < DD) {
        const float M = fmaxf(fmaxf(mred[0], mred[1]), fmaxf(mred[2], mred[3]));
        float L = 0.f, O = 0.f;
#pragma unroll
        for (int wv = 0; wv < 4; ++wv) {
            const float e = expf(mred[wv] - M);   // wave with no chunks: m=-inf -> e=0
            L += e * lred[wv];
            O += e * ored[wv][tid];
        }
        out[row * DD + tid] = O / L;
    }
}

extern "C" void kernel_launch(void* const* d_in, const int* in_sizes, int n_in,
                              void* d_out, int out_size, void* d_ws, size_t ws_size,
                              hipStream_t stream) {
    const float* x  = (const float*)d_in[0];
    const float* W1 = (const float*)d_in[1];
    const float* b1 = (const float*)d_in[2];
    const float* W2 = (const float*)d_in[3];
    const float* b2 = (const float*)d_in[4];
    float* outp = (float*)d_out;

    float* A  = (float*)d_ws;                 // 2048*96 fp32
    float* Bb = A + ROWS * TWO_D;             // 2048*96 fp32  (total 1.5 MB)

    precompute_kernel<<<ROWS, TWO_D, 0, stream>>>(x, W1, b1, A, Bb);
    pair_softmax_kernel<<<ROWS, 256, 0, stream>>>(A, Bb, W2, b2, outp);
}

// Round 3
// 109.070 us; speedup vs baseline: 1.4143x; 1.4143x over previous
//
#include <hip/hip_runtime.h>
#include <hip/hip_bf16.h>
#include <math.h>

#define DD 48
#define NN 512
#define TWO_D 96
#define ROWS 2048   // B*N = 4*512

typedef __attribute__((ext_vector_type(8))) short bf16x8;
typedef __attribute__((ext_vector_type(4))) float f32x4;

// fast GELU: sigmoid form of the tanh approximation.
// h = u * sigmoid(1.59577*u + 0.0713548*u^3); max |err| vs exact-erf gelu ~5e-4 for |u|<3.
// 7 VALU ops (2 on trans pipe).
__device__ __forceinline__ float gelu_fast(float u) {
    const float u2 = u * u;
    const float yn = u * fmaf(u2, -0.10295347f, -2.3022587f);  // -(2z)*log2(e)
    const float e = __builtin_amdgcn_exp2f(yn);
    return u * __builtin_amdgcn_rcpf(1.0f + e);
}

// Kernel 1: A[r][t] = x_r @ W1[0:48, t] + b1[t];  Bb[r][t] = x_r @ W1[48:96, t]
// 512 blocks x 256 threads; wave w handles row blockIdx*4 + w.
__global__ __launch_bounds__(256) void precompute_kernel(
        const float* __restrict__ x,
        const float* __restrict__ W1,
        const float* __restrict__ b1,
        float* __restrict__ Aout,
        float* __restrict__ Bout) {
    const int wave = threadIdx.x >> 6;
    const int lane = threadIdx.x & 63;
    const int row = blockIdx.x * 4 + wave;
    __shared__ float xs[4][DD];
    if (threadIdx.x < 4 * DD)
        xs[threadIdx.x / DD][threadIdx.x % DD] = x[blockIdx.x * 4 * DD + threadIdx.x];
    __syncthreads();
    for (int t = lane; t < TWO_D; t += 64) {
        float a0 = 0.f, a1 = 0.f;
#pragma unroll 8
        for (int k = 0; k < DD; ++k) {
            const float xv = xs[wave][k];
            a0 = fmaf(xv, W1[k * TWO_D + t], a0);
            a1 = fmaf(xv, W1[(DD + k) * TWO_D + t], a1);
        }
        Aout[row * TWO_D + t] = a0 + b1[t];
        Bout[row * TWO_D + t] = a1;
    }
}

// Kernel 2: one block per (b,i) row, heaviest rows first. 4 waves; wave w owns
// j-chunks w, w+4, ... Each lane (n=lane&15, q=lane>>4) computes its MFMA
// A-fragment H[n][ks*32+q*8+0..7] = gelu(A_i + Bb_{j0+n}) DIRECTLY in registers
// (no LDS round-trip), then 9 MFMA -> P[16][48], then online softmax over j.
__global__ __launch_bounds__(256) void pair_softmax_kernel(
        const float* __restrict__ Arow,
        const float* __restrict__ Brow,
        const float* __restrict__ W2,
        const float* __restrict__ b2,
        float* __restrict__ out) {
    const int row = (ROWS - 1) - blockIdx.x;   // heavy (large i) rows dispatched first
    const int i = row & (NN - 1);
    const int tid = threadIdx.x;
    const int wave = tid >> 6;
    const int lane = tid & 63;
    const int n = lane & 15;   // MFMA A-row / C col index
    const int q = lane >> 4;   // quad
    const int q8 = q * 8;

    // j rows live in the SAME batch: global j-row = (row - i) + j
    const float* __restrict__ Bbase = Brow + (size_t)(row - i) * TWO_D;

    __shared__ __align__(16) __hip_bfloat16 W2Ts[DD * TWO_D];   // [f][k], 9216 B
    __shared__ float mred[4], lred[4], ored[4][DD];

    // Stage W2^T (bf16) into LDS (once per block)
    for (int idx = tid; idx < TWO_D * DD; idx += 256) {
        const int k = idx / DD;
        const int f = idx - k * DD;
        W2Ts[f * TWO_D + k] = __float2bfloat16(W2[idx]);
    }
    __syncthreads();

    // B fragments: B[k][f], lane n = f (col), k = ks*32 + q*8 + 0..7
    bf16x8 bfrag[3][3];
#pragma unroll
    for (int t = 0; t < 3; ++t)
#pragma unroll
        for (int ks = 0; ks < 3; ++ks)
            bfrag[t][ks] = *(const bf16x8*)&W2Ts[(t * 16 + n) * TWO_D + ks * 32 + q8];
    float b2v[3];
#pragma unroll
    for (int t = 0; t < 3; ++t) b2v[t] = b2[t * 16 + n];

    // A_i values this lane needs: k = ks*32 + q*8 + 0..7  (register-resident)
    float av[3][8];
#pragma unroll
    for (int ks = 0; ks < 3; ++ks) {
        const float4 a0 = *(const float4*)&Arow[(size_t)row * TWO_D + ks * 32 + q8];
        const float4 a1 = *(const float4*)&Arow[(size_t)row * TWO_D + ks * 32 + q8 + 4];
        av[ks][0] = a0.x; av[ks][1] = a0.y; av[ks][2] = a0.z; av[ks][3] = a0.w;
        av[ks][4] = a1.x; av[ks][5] = a1.y; av[ks][6] = a1.z; av[ks][7] = a1.w;
    }

    float m_run = -INFINITY, l_run = 0.f;
    float o_run[3] = {0.f, 0.f, 0.f};

    const int nchunks = (i + 16) >> 4;   // ceil((i+1)/16); j0+15 <= 511 always

    for (int c = wave; c < nchunks; c += 4) {
        const int j0 = c << 4;
        const float* __restrict__ Bj = Bbase + (size_t)(j0 + n) * TWO_D;

        // ---- Phase A+B fused: A-frag in registers, 9 MFMA
        f32x4 acc[3] = {{0.f,0.f,0.f,0.f},{0.f,0.f,0.f,0.f},{0.f,0.f,0.f,0.f}};
#pragma unroll
        for (int ks = 0; ks < 3; ++ks) {
            const float4 bv0 = *(const float4*)&Bj[ks * 32 + q8];
            const float4 bv1 = *(const float4*)&Bj[ks * 32 + q8 + 4];
            float h[8];
            h[0] = gelu_fast(av[ks][0] + bv0.x);
            h[1] = gelu_fast(av[ks][1] + bv0.y);
            h[2] = gelu_fast(av[ks][2] + bv0.z);
            h[3] = gelu_fast(av[ks][3] + bv0.w);
            h[4] = gelu_fast(av[ks][4] + bv1.x);
            h[5] = gelu_fast(av[ks][5] + bv1.y);
            h[6] = gelu_fast(av[ks][6] + bv1.z);
            h[7] = gelu_fast(av[ks][7] + bv1.w);
            union { bf16x8 v; __hip_bfloat162 h2[4]; } af;
#pragma unroll
            for (int p = 0; p < 4; ++p)
                af.h2[p] = __float22bfloat162_rn(make_float2(h[2 * p], h[2 * p + 1]));
            acc[0] = __builtin_amdgcn_mfma_f32_16x16x32_bf16(af.v, bfrag[0][ks], acc[0], 0, 0, 0);
            acc[1] = __builtin_amdgcn_mfma_f32_16x16x32_bf16(af.v, bfrag[1][ks], acc[1], 0, 0, 0);
            acc[2] = __builtin_amdgcn_mfma_f32_16x16x32_bf16(af.v, bfrag[2][ks], acc[2], 0, 0, 0);
        }

        // ---- Epilogue: C/D layout row j_local = 4q+r, col f = t*16+n
        float pv[3][4];
        float ss[4];
#pragma unroll
        for (int r = 0; r < 4; ++r) {
            float s = 0.f;
#pragma unroll
            for (int t = 0; t < 3; ++t) {
                const float p = acc[t][r] + b2v[t];
                pv[t][r] = p;
                s = fmaf(p, p, s);
            }
            ss[r] = s;
        }
        // sum of squares over all 48 f: reduce across the 16 lanes of the quad
#pragma unroll
        for (int d = 1; d <= 8; d <<= 1) {
#pragma unroll
            for (int r = 0; r < 4; ++r) ss[r] += __shfl_xor(ss[r], d);
        }
        float w[4];
#pragma unroll
        for (int r = 0; r < 4; ++r) {
            const int j = j0 + 4 * q + r;
            w[r] = (j <= i) ? sqrtf(ss[r]) : -1e30f;
        }
        float wm = fmaxf(fmaxf(w[0], w[1]), fmaxf(w[2], w[3]));
        wm = fmaxf(wm, __shfl_xor(wm, 16));
        wm = fmaxf(wm, __shfl_xor(wm, 32));
        const float mnew = fmaxf(m_run, wm);          // >= 0 always (norms >= 0)
        const float alpha = __expf(m_run - mnew);     // first chunk: exp(-inf)=0, l/o are 0
        float ew[4];
#pragma unroll
        for (int r = 0; r < 4; ++r) ew[r] = __expf(w[r] - mnew);  // masked -> 0 exactly
        float es = ew[0] + ew[1] + ew[2] + ew[3];
        es += __shfl_xor(es, 16);
        es += __shfl_xor(es, 32);
        l_run = l_run * alpha + es;
#pragma unroll
        for (int t = 0; t < 3; ++t) {
            float op = ew[0]*pv[t][0] + ew[1]*pv[t][1] + ew[2]*pv[t][2] + ew[3]*pv[t][3];
            op += __shfl_xor(op, 16);
            op += __shfl_xor(op, 32);
            o_run[t] = o_run[t] * alpha + op;
        }
        m_run = mnew;
    }

    // ---- Merge the 4 per-wave online-softmax states
    if (lane == 0) { mred[wave] = m_run; lred[wave] = l_run; }
    if (q == 0) {
#pragma unroll
        for (int t = 0; t < 3; ++t) ored[wave][t * 16 + n] = o_run[t];
    }
    __syncthreads();
    if (tid < DD) {
        const float M = fmaxf(fmaxf(mred[0], mred[1]), fmaxf(mred[2], mred[3]));
        float L = 0.f, O = 0.f;
#pragma unroll
        for (int wv = 0; wv < 4; ++wv) {
            const float e = __expf(mred[wv] - M);   // wave with no chunks: m=-inf -> e=0
            L += e * lred[wv];
            O += e * ored[wv][tid];
        }
        out[row * DD + tid] = O / L;
    }
}

extern "C" void kernel_launch(void* const* d_in, const int* in_sizes, int n_in,
                              void* d_out, int out_size, void* d_ws, size_t ws_size,
                              hipStream_t stream) {
    const float* x  = (const float*)d_in[0];
    const float* W1 = (const float*)d_in[1];
    const float* b1 = (const float*)d_in[2];
    const float* W2 = (const float*)d_in[3];
    const float* b2 = (const float*)d_in[4];
    float* outp = (float*)d_out;

    float* A  = (float*)d_ws;                 // 2048*96 fp32
    float* Bb = A + ROWS * TWO_D;             // 2048*96 fp32  (total 1.5 MB)

    precompute_kernel<<<ROWS / 4, 256, 0, stream>>>(x, W1, b1, A, Bb);
    pair_softmax_kernel<<<ROWS, 256, 0, stream>>>(A, Bb, W2, b2, outp);
}